// Round 1
// baseline (993.539 us; speedup 1.0000x reference)
//
#include <hip/hip_runtime.h>

#define NN 100000
#define NE 1600000
#define HD 128
#define NG 128
#define BN_EPS 1e-5f

// ---------------- degree histogram ----------------
__global__ __launch_bounds__(256) void k_hist(const int* __restrict__ dst, int* __restrict__ deg) {
    int e = blockIdx.x * 256 + threadIdx.x;
    if (e < NE) atomicAdd(&deg[dst[e]], 1);
}

// ---------------- dinv = rsqrt(deg+1) ----------------
__global__ __launch_bounds__(256) void k_dinv(const int* __restrict__ deg, float* __restrict__ dinv) {
    int n = blockIdx.x * 256 + threadIdx.x;
    if (n < NN) dinv[n] = rsqrtf((float)deg[n] + 1.0f);
}

// ---------------- prefix scan (3 kernels) ----------------
__global__ __launch_bounds__(256) void k_blockscan(const int* __restrict__ deg, int* __restrict__ excl,
                                                   int* __restrict__ bsum) {
    __shared__ int s[256];
    int t = threadIdx.x;
    int i = blockIdx.x * 256 + t;
    int v = (i < NN) ? deg[i] : 0;
    s[t] = v;
    __syncthreads();
    for (int o = 1; o < 256; o <<= 1) {
        int add = (t >= o) ? s[t - o] : 0;
        __syncthreads();
        s[t] += add;
        __syncthreads();
    }
    if (i < NN) excl[i] = s[t] - v;
    if (t == 255) bsum[blockIdx.x] = s[255];
}

__global__ void k_scanb(int* __restrict__ bsum, int nb, int* __restrict__ row_start) {
    if (threadIdx.x == 0 && blockIdx.x == 0) {
        int run = 0;
        for (int i = 0; i < nb; ++i) { int t = bsum[i]; bsum[i] = run; run += t; }
        row_start[NN] = run;  // == NE
    }
}

__global__ __launch_bounds__(256) void k_scanadd(int* __restrict__ row_start, const int* __restrict__ bsum) {
    int i = blockIdx.x * 256 + threadIdx.x;
    if (i < NN) row_start[i] += bsum[blockIdx.x];
}

// ---------------- CSR fill (sorted by dst) ----------------
__global__ __launch_bounds__(256) void k_fill(const int* __restrict__ src, const int* __restrict__ dst,
                                              const float* __restrict__ dinv, const int* __restrict__ row_start,
                                              int* __restrict__ cursor, int* __restrict__ esrc,
                                              float* __restrict__ ecoef) {
    int e = blockIdx.x * 256 + threadIdx.x;
    if (e >= NE) return;
    int s = src[e], d = dst[e];
    float cf = dinv[s] * dinv[d];
    int pos = row_start[d] + atomicAdd(&cursor[d], 1);
    esrc[pos] = s;
    ecoef[pos] = cf;
}

// ---------------- GEMM: Y[N][128] = X[N][K=128] @ W[128][128], row stride ldx ----------------
__global__ __launch_bounds__(256) void k_gemm(const float* __restrict__ X, int ldx,
                                              const float* __restrict__ W, float* __restrict__ Y) {
    __shared__ float Xs[64][33];
    __shared__ float Ws[32][132];
    int tid = threadIdx.x;
    int tx = tid & 15, ty = tid >> 4;  // tx: col-group (8 cols), ty: row-group (4 rows)
    int r0 = blockIdx.x * 64;
    float acc[4][8];
#pragma unroll
    for (int i = 0; i < 4; ++i)
#pragma unroll
        for (int j = 0; j < 8; ++j) acc[i][j] = 0.f;

    for (int k0 = 0; k0 < 128; k0 += 32) {
        // load X tile 64x32
        for (int f = tid; f < 512; f += 256) {
            int row = f >> 3, kq = f & 7;
            int gr = r0 + row;
            float4 v = make_float4(0.f, 0.f, 0.f, 0.f);
            if (gr < NN) v = *(const float4*)(X + (size_t)gr * ldx + k0 + kq * 4);
            Xs[row][kq * 4 + 0] = v.x;
            Xs[row][kq * 4 + 1] = v.y;
            Xs[row][kq * 4 + 2] = v.z;
            Xs[row][kq * 4 + 3] = v.w;
        }
        // load W tile 32x128
        for (int f = tid; f < 1024; f += 256) {
            int wr = f >> 5, wc = f & 31;
            float4 v = *(const float4*)(W + (size_t)(k0 + wr) * 128 + wc * 4);
            *(float4*)&Ws[wr][wc * 4] = v;
        }
        __syncthreads();
#pragma unroll
        for (int kk = 0; kk < 32; ++kk) {
            float4 w0 = *(const float4*)&Ws[kk][tx * 8];
            float4 w1 = *(const float4*)&Ws[kk][tx * 8 + 4];
#pragma unroll
            for (int i = 0; i < 4; ++i) {
                float xv = Xs[ty * 4 + i][kk];
                acc[i][0] += xv * w0.x; acc[i][1] += xv * w0.y;
                acc[i][2] += xv * w0.z; acc[i][3] += xv * w0.w;
                acc[i][4] += xv * w1.x; acc[i][5] += xv * w1.y;
                acc[i][6] += xv * w1.z; acc[i][7] += xv * w1.w;
            }
        }
        __syncthreads();
    }
#pragma unroll
    for (int i = 0; i < 4; ++i) {
        int gr = r0 + ty * 4 + i;
        if (gr < NN) {
            float* yp = Y + (size_t)gr * 128 + tx * 8;
            *(float4*)yp       = make_float4(acc[i][0], acc[i][1], acc[i][2], acc[i][3]);
            *(float4*)(yp + 4) = make_float4(acc[i][4], acc[i][5], acc[i][6], acc[i][7]);
        }
    }
}

// ---------------- aggregate + bias + relu ----------------
__global__ __launch_bounds__(128) void k_agg(const float* __restrict__ hm, const int* __restrict__ esrc,
                                             const float* __restrict__ ecoef, const int* __restrict__ rs,
                                             const float* __restrict__ dinv, const float* __restrict__ bias,
                                             float* __restrict__ act) {
    int tx = threadIdx.x & 31, ty = threadIdx.x >> 5;
    int n = blockIdx.x * 4 + ty;
    if (n >= NN) return;
    int c4 = tx * 4;
    float di = dinv[n];
    float sc = di * di;
    float4 a = *(const float4*)(hm + (size_t)n * 128 + c4);
    float sx = a.x * sc, sy = a.y * sc, sz = a.z * sc, sw = a.w * sc;
    int i = rs[n], e = rs[n + 1];
    for (; i + 4 <= e; i += 4) {
        int s0 = esrc[i], s1 = esrc[i + 1], s2 = esrc[i + 2], s3 = esrc[i + 3];
        float c0 = ecoef[i], c1 = ecoef[i + 1], c2 = ecoef[i + 2], c3 = ecoef[i + 3];
        float4 v0 = *(const float4*)(hm + (size_t)s0 * 128 + c4);
        float4 v1 = *(const float4*)(hm + (size_t)s1 * 128 + c4);
        float4 v2 = *(const float4*)(hm + (size_t)s2 * 128 + c4);
        float4 v3 = *(const float4*)(hm + (size_t)s3 * 128 + c4);
        sx += c0 * v0.x + c1 * v1.x + c2 * v2.x + c3 * v3.x;
        sy += c0 * v0.y + c1 * v1.y + c2 * v2.y + c3 * v3.y;
        sz += c0 * v0.z + c1 * v1.z + c2 * v2.z + c3 * v3.z;
        sw += c0 * v0.w + c1 * v1.w + c2 * v2.w + c3 * v3.w;
    }
    for (; i < e; ++i) {
        int s0 = esrc[i];
        float c0 = ecoef[i];
        float4 v0 = *(const float4*)(hm + (size_t)s0 * 128 + c4);
        sx += c0 * v0.x; sy += c0 * v0.y; sz += c0 * v0.z; sw += c0 * v0.w;
    }
    float4 b4 = *(const float4*)(bias + c4);
    sx = fmaxf(sx + b4.x, 0.f);
    sy = fmaxf(sy + b4.y, 0.f);
    sz = fmaxf(sz + b4.z, 0.f);
    sw = fmaxf(sw + b4.w, 0.f);
    *(float4*)(act + (size_t)n * 128 + c4) = make_float4(sx, sy, sz, sw);
}

// ---------------- BN stats ----------------
__global__ __launch_bounds__(128) void k_stats(const float* __restrict__ act, float* __restrict__ bnsum,
                                               float* __restrict__ bnsq) {
    int c = threadIdx.x;
    float s = 0.f, q = 0.f;
    for (int n = blockIdx.x; n < NN; n += gridDim.x) {
        float a = act[(size_t)n * 128 + c];
        s += a;
        q += a * a;
    }
    atomicAdd(&bnsum[c], s);
    atomicAdd(&bnsq[c], q);
}

// ---------------- normalize + write h_cat + pool ----------------
__global__ __launch_bounds__(128) void k_norm(const float* __restrict__ act, const float* __restrict__ bnsum,
                                              const float* __restrict__ bnsq, const float* __restrict__ gam,
                                              const float* __restrict__ bet, const int* __restrict__ batch,
                                              float* __restrict__ out, float* __restrict__ gout, int lofs) {
    int c = threadIdx.x;
    int n0 = blockIdx.x * 64;
    if (n0 >= NN) return;
    int n1 = n0 + 64; if (n1 > NN) n1 = NN;
    float mean = bnsum[c] / (float)NN;
    float var = bnsq[c] / (float)NN - mean * mean;
    float rstd = rsqrtf(fmaxf(var, 0.f) + BN_EPS);
    float scale = gam[c] * rstd;
    float shift = bet[c] - mean * scale;
    int cur = batch[n0];
    float acc = 0.f;
    for (int n = n0; n < n1; ++n) {
        float z = act[(size_t)n * 128 + c] * scale + shift;
        out[(size_t)n * 384 + lofs + c] = z;
        int bn = batch[n];
        if (bn != cur) {
            atomicAdd(&gout[(size_t)cur * 384 + lofs + c], acc);
            acc = 0.f;
            cur = bn;
        }
        acc += z;
    }
    atomicAdd(&gout[(size_t)cur * 384 + lofs + c], acc);
}

extern "C" void kernel_launch(void* const* d_in, const int* in_sizes, int n_in,
                              void* d_out, int out_size, void* d_ws, size_t ws_size,
                              hipStream_t stream) {
    const float* x = (const float*)d_in[0];
    const int* ei = (const int*)d_in[1];
    const int* src = ei;
    const int* dst = ei + NE;
    const int* batch = (const int*)d_in[2];
    const float *W[3], *b[3], *g[3], *beta[3];
    for (int l = 0; l < 3; ++l) {
        W[l]    = (const float*)d_in[3 + 4 * l];
        b[l]    = (const float*)d_in[4 + 4 * l];
        g[l]    = (const float*)d_in[5 + 4 * l];
        beta[l] = (const float*)d_in[6 + 4 * l];
    }
    float* out = (float*)d_out;
    float* gout = out + (size_t)NN * 384;

    char* ws = (char*)d_ws;
    size_t off = 0;
    auto alloc = [&](size_t bytes) -> char* {
        off = (off + 255) & ~(size_t)255;
        char* p = ws + off;
        off += bytes;
        return p;
    };
    float* hm        = (float*)alloc((size_t)NN * 128 * 4);
    float* act       = (float*)alloc((size_t)NN * 128 * 4);
    int*   esrc      = (int*)alloc((size_t)NE * 4);
    float* ecoef     = (float*)alloc((size_t)NE * 4);
    int*   deg       = (int*)alloc((size_t)NN * 4);
    int*   cursor    = (int*)alloc((size_t)NN * 4);
    int*   row_start = (int*)alloc((size_t)(NN + 1) * 4);
    float* dinv      = (float*)alloc((size_t)NN * 4);
    int*   bsum      = (int*)alloc(512 * 4);
    float* bnst      = (float*)alloc(6 * 128 * 4);
    (void)ws_size;

    hipMemsetAsync(deg, 0, (size_t)NN * 4, stream);
    hipMemsetAsync(cursor, 0, (size_t)NN * 4, stream);
    hipMemsetAsync(bnst, 0, 6 * 128 * 4, stream);
    hipMemsetAsync(gout, 0, (size_t)NG * 384 * 4, stream);

    int nbN = (NN + 255) / 256;     // 391
    int nbE = (NE + 255) / 256;     // 6250

    k_hist<<<nbE, 256, 0, stream>>>(dst, deg);
    k_dinv<<<nbN, 256, 0, stream>>>(deg, dinv);
    k_blockscan<<<nbN, 256, 0, stream>>>(deg, row_start, bsum);
    k_scanb<<<1, 1, 0, stream>>>(bsum, nbN, row_start);
    k_scanadd<<<nbN, 256, 0, stream>>>(row_start, bsum);
    k_fill<<<nbE, 256, 0, stream>>>(src, dst, dinv, row_start, cursor, esrc, ecoef);

    for (int l = 0; l < 3; ++l) {
        const float* X = (l == 0) ? x : (out + (size_t)(l - 1) * 128);
        int ldx = (l == 0) ? 128 : 384;
        k_gemm<<<(NN + 63) / 64, 256, 0, stream>>>(X, ldx, W[l], hm);
        k_agg<<<(NN + 3) / 4, 128, 0, stream>>>(hm, esrc, ecoef, row_start, dinv, b[l], act);
        k_stats<<<1024, 128, 0, stream>>>(act, bnst + l * 256, bnst + l * 256 + 128);
        k_norm<<<(NN + 63) / 64, 128, 0, stream>>>(act, bnst + l * 256, bnst + l * 256 + 128,
                                                   g[l], beta[l], batch, out, gout, l * 128);
    }
}

// Round 2
// 799.572 us; speedup vs baseline: 1.2426x; 1.2426x over previous
//
#include <hip/hip_runtime.h>

#define NN 100000
#define NE 1600000
#define NG 128
#define BN_EPS 1e-5f
#define NTILES 6250   // NN / 16, exact

static __device__ __forceinline__ unsigned short f2bf(float f) {
    unsigned u = __float_as_uint(f);
    u += 0x7fffu + ((u >> 16) & 1u);   // round-to-nearest-even
    return (unsigned short)(u >> 16);
}
static __device__ __forceinline__ unsigned packbf(float a, float b) {
    return (unsigned)f2bf(a) | ((unsigned)f2bf(b) << 16);
}
static __device__ __forceinline__ float bf_lo(unsigned u) { return __uint_as_float(u << 16); }
static __device__ __forceinline__ float bf_hi(unsigned u) { return __uint_as_float(u & 0xffff0000u); }

// ---------------- degree histogram ----------------
__global__ __launch_bounds__(256) void k_hist(const int* __restrict__ dst, int* __restrict__ deg) {
    int e = blockIdx.x * 256 + threadIdx.x;
    if (e < NE) atomicAdd(&deg[dst[e]], 1);
}

// ---------------- dinv = rsqrt(deg+1) ----------------
__global__ __launch_bounds__(256) void k_dinv(const int* __restrict__ deg, float* __restrict__ dinv) {
    int n = blockIdx.x * 256 + threadIdx.x;
    if (n < NN) dinv[n] = rsqrtf((float)deg[n] + 1.0f);
}

// ---------------- prefix scan ----------------
__global__ __launch_bounds__(256) void k_blockscan(const int* __restrict__ deg, int* __restrict__ excl,
                                                   int* __restrict__ bsum) {
    __shared__ int s[256];
    int t = threadIdx.x;
    int i = blockIdx.x * 256 + t;
    int v = (i < NN) ? deg[i] : 0;
    s[t] = v;
    __syncthreads();
    for (int o = 1; o < 256; o <<= 1) {
        int add = (t >= o) ? s[t - o] : 0;
        __syncthreads();
        s[t] += add;
        __syncthreads();
    }
    if (i < NN) excl[i] = s[t] - v;
    if (t == 255) bsum[blockIdx.x] = s[255];
}

// single-block parallel scan over block sums (nb <= 512)
__global__ __launch_bounds__(512) void k_scanb(int* __restrict__ bsum, int nb, int* __restrict__ row_start) {
    __shared__ int s[512];
    int t = threadIdx.x;
    int v = (t < nb) ? bsum[t] : 0;
    s[t] = v;
    __syncthreads();
    for (int o = 1; o < 512; o <<= 1) {
        int add = (t >= o) ? s[t - o] : 0;
        __syncthreads();
        s[t] += add;
        __syncthreads();
    }
    if (t < nb) bsum[t] = s[t] - v;          // exclusive
    if (t == nb - 1) row_start[NN] = s[t];   // total == NE
}

__global__ __launch_bounds__(256) void k_scanadd(int* __restrict__ row_start, const int* __restrict__ bsum) {
    int i = blockIdx.x * 256 + threadIdx.x;
    if (i < NN) row_start[i] += bsum[blockIdx.x];
}

// ---------------- CSR fill (packed src+coef records) ----------------
__global__ __launch_bounds__(256) void k_fill(const int* __restrict__ src, const int* __restrict__ dst,
                                              const float* __restrict__ dinv, const int* __restrict__ row_start,
                                              int* __restrict__ cursor, int2* __restrict__ epair) {
    int e = blockIdx.x * 256 + threadIdx.x;
    if (e >= NE) return;
    int s = src[e], d = dst[e];
    float cf = dinv[s] * dinv[d];
    int pos = row_start[d] + atomicAdd(&cursor[d], 1);
    epair[pos] = make_int2(s, __float_as_int(cf));
}

// ---------------- GEMM: Ybf16[N][128] = X[N][K=128] @ W[128][128] ----------------
__global__ __launch_bounds__(256) void k_gemm(const float* __restrict__ X, int ldx,
                                              const float* __restrict__ W, uint4* __restrict__ Y) {
    __shared__ float Xs[64][33];
    __shared__ float Ws[32][132];
    int tid = threadIdx.x;
    int tx = tid & 15, ty = tid >> 4;
    int r0 = blockIdx.x * 64;
    float acc[4][8];
#pragma unroll
    for (int i = 0; i < 4; ++i)
#pragma unroll
        for (int j = 0; j < 8; ++j) acc[i][j] = 0.f;

    for (int k0 = 0; k0 < 128; k0 += 32) {
        for (int f = tid; f < 512; f += 256) {
            int row = f >> 3, kq = f & 7;
            int gr = r0 + row;
            float4 v = make_float4(0.f, 0.f, 0.f, 0.f);
            if (gr < NN) v = *(const float4*)(X + (size_t)gr * ldx + k0 + kq * 4);
            Xs[row][kq * 4 + 0] = v.x;
            Xs[row][kq * 4 + 1] = v.y;
            Xs[row][kq * 4 + 2] = v.z;
            Xs[row][kq * 4 + 3] = v.w;
        }
        for (int f = tid; f < 1024; f += 256) {
            int wr = f >> 5, wc = f & 31;
            float4 v = *(const float4*)(W + (size_t)(k0 + wr) * 128 + wc * 4);
            *(float4*)&Ws[wr][wc * 4] = v;
        }
        __syncthreads();
#pragma unroll
        for (int kk = 0; kk < 32; ++kk) {
            float4 w0 = *(const float4*)&Ws[kk][tx * 8];
            float4 w1 = *(const float4*)&Ws[kk][tx * 8 + 4];
#pragma unroll
            for (int i = 0; i < 4; ++i) {
                float xv = Xs[ty * 4 + i][kk];
                acc[i][0] += xv * w0.x; acc[i][1] += xv * w0.y;
                acc[i][2] += xv * w0.z; acc[i][3] += xv * w0.w;
                acc[i][4] += xv * w1.x; acc[i][5] += xv * w1.y;
                acc[i][6] += xv * w1.z; acc[i][7] += xv * w1.w;
            }
        }
        __syncthreads();
    }
#pragma unroll
    for (int i = 0; i < 4; ++i) {
        int gr = r0 + ty * 4 + i;
        if (gr < NN) {
            uint4 o;
            o.x = packbf(acc[i][0], acc[i][1]);
            o.y = packbf(acc[i][2], acc[i][3]);
            o.z = packbf(acc[i][4], acc[i][5]);
            o.w = packbf(acc[i][6], acc[i][7]);
            Y[(size_t)gr * 16 + tx] = o;
        }
    }
}

// ---------------- aggregate + bias + relu + fused BN stats ----------------
// 256 threads: 16 lanes/node (8 bf16 channels each), 16 nodes/tile, grid-stride over tiles
__global__ __launch_bounds__(256) void k_agg(const uint4* __restrict__ hm, const int2* __restrict__ epair,
                                             const int* __restrict__ rs, const float* __restrict__ dinv,
                                             const float* __restrict__ bias, float* __restrict__ act,
                                             float* __restrict__ bnsum, float* __restrict__ bnsq) {
    __shared__ float ssum[128], ssq[128];
    int tid = threadIdx.x;
    if (tid < 128) { ssum[tid] = 0.f; ssq[tid] = 0.f; }
    __syncthreads();
    int tx = tid & 15, ny = tid >> 4;
    float b4[8];
    {
        float4 b0 = *(const float4*)(bias + tx * 8);
        float4 b1 = *(const float4*)(bias + tx * 8 + 4);
        b4[0] = b0.x; b4[1] = b0.y; b4[2] = b0.z; b4[3] = b0.w;
        b4[4] = b1.x; b4[5] = b1.y; b4[6] = b1.z; b4[7] = b1.w;
    }
    float st_s[8], st_q[8];
#pragma unroll
    for (int k = 0; k < 8; ++k) { st_s[k] = 0.f; st_q[k] = 0.f; }

    for (int tile = blockIdx.x; tile < NTILES; tile += gridDim.x) {
        int n = tile * 16 + ny;
        float di = dinv[n];
        float sc = di * di;
        float a[8];
        uint4 h = hm[(size_t)n * 16 + tx];
        a[0] = sc * bf_lo(h.x); a[1] = sc * bf_hi(h.x);
        a[2] = sc * bf_lo(h.y); a[3] = sc * bf_hi(h.y);
        a[4] = sc * bf_lo(h.z); a[5] = sc * bf_hi(h.z);
        a[6] = sc * bf_lo(h.w); a[7] = sc * bf_hi(h.w);
        int i = rs[n], e = rs[n + 1];
        for (; i + 4 <= e; i += 4) {
            int2 e0 = epair[i], e1 = epair[i + 1], e2 = epair[i + 2], e3 = epair[i + 3];
            uint4 v0 = hm[(size_t)e0.x * 16 + tx];
            uint4 v1 = hm[(size_t)e1.x * 16 + tx];
            uint4 v2 = hm[(size_t)e2.x * 16 + tx];
            uint4 v3 = hm[(size_t)e3.x * 16 + tx];
            float c0 = __int_as_float(e0.y), c1 = __int_as_float(e1.y);
            float c2 = __int_as_float(e2.y), c3 = __int_as_float(e3.y);
            a[0] += c0 * bf_lo(v0.x) + c1 * bf_lo(v1.x) + c2 * bf_lo(v2.x) + c3 * bf_lo(v3.x);
            a[1] += c0 * bf_hi(v0.x) + c1 * bf_hi(v1.x) + c2 * bf_hi(v2.x) + c3 * bf_hi(v3.x);
            a[2] += c0 * bf_lo(v0.y) + c1 * bf_lo(v1.y) + c2 * bf_lo(v2.y) + c3 * bf_lo(v3.y);
            a[3] += c0 * bf_hi(v0.y) + c1 * bf_hi(v1.y) + c2 * bf_hi(v2.y) + c3 * bf_hi(v3.y);
            a[4] += c0 * bf_lo(v0.z) + c1 * bf_lo(v1.z) + c2 * bf_lo(v2.z) + c3 * bf_lo(v3.z);
            a[5] += c0 * bf_hi(v0.z) + c1 * bf_hi(v1.z) + c2 * bf_hi(v2.z) + c3 * bf_hi(v3.z);
            a[6] += c0 * bf_lo(v0.w) + c1 * bf_lo(v1.w) + c2 * bf_lo(v2.w) + c3 * bf_lo(v3.w);
            a[7] += c0 * bf_hi(v0.w) + c1 * bf_hi(v1.w) + c2 * bf_hi(v2.w) + c3 * bf_hi(v3.w);
        }
        for (; i < e; ++i) {
            int2 e0 = epair[i];
            uint4 v0 = hm[(size_t)e0.x * 16 + tx];
            float c0 = __int_as_float(e0.y);
            a[0] += c0 * bf_lo(v0.x); a[1] += c0 * bf_hi(v0.x);
            a[2] += c0 * bf_lo(v0.y); a[3] += c0 * bf_hi(v0.y);
            a[4] += c0 * bf_lo(v0.z); a[5] += c0 * bf_hi(v0.z);
            a[6] += c0 * bf_lo(v0.w); a[7] += c0 * bf_hi(v0.w);
        }
#pragma unroll
        for (int k = 0; k < 8; ++k) {
            float v = fmaxf(a[k] + b4[k], 0.f);
            a[k] = v;
            st_s[k] += v;
            st_q[k] += v * v;
        }
        float* ap = act + (size_t)n * 128 + tx * 8;
        *(float4*)ap       = make_float4(a[0], a[1], a[2], a[3]);
        *(float4*)(ap + 4) = make_float4(a[4], a[5], a[6], a[7]);
    }
#pragma unroll
    for (int k = 0; k < 8; ++k) {
        atomicAdd(&ssum[tx * 8 + k], st_s[k]);
        atomicAdd(&ssq[tx * 8 + k], st_q[k]);
    }
    __syncthreads();
    if (tid < 128) {
        atomicAdd(&bnsum[tid], ssum[tid]);
        atomicAdd(&bnsq[tid], ssq[tid]);
    }
}

// ---------------- normalize + write h_cat + pool ----------------
__global__ __launch_bounds__(128) void k_norm(const float* __restrict__ act, const float* __restrict__ bnsum,
                                              const float* __restrict__ bnsq, const float* __restrict__ gam,
                                              const float* __restrict__ bet, const int* __restrict__ batch,
                                              float* __restrict__ out, float* __restrict__ gout, int lofs) {
    int c = threadIdx.x;
    int n0 = blockIdx.x * 64;
    if (n0 >= NN) return;
    int n1 = n0 + 64; if (n1 > NN) n1 = NN;
    float mean = bnsum[c] / (float)NN;
    float var = bnsq[c] / (float)NN - mean * mean;
    float rstd = rsqrtf(fmaxf(var, 0.f) + BN_EPS);
    float scale = gam[c] * rstd;
    float shift = bet[c] - mean * scale;
    int cur = batch[n0];
    float acc = 0.f;
    for (int n = n0; n < n1; ++n) {
        float z = act[(size_t)n * 128 + c] * scale + shift;
        out[(size_t)n * 384 + lofs + c] = z;
        int bn = batch[n];
        if (bn != cur) {
            atomicAdd(&gout[(size_t)cur * 384 + lofs + c], acc);
            acc = 0.f;
            cur = bn;
        }
        acc += z;
    }
    atomicAdd(&gout[(size_t)cur * 384 + lofs + c], acc);
}

extern "C" void kernel_launch(void* const* d_in, const int* in_sizes, int n_in,
                              void* d_out, int out_size, void* d_ws, size_t ws_size,
                              hipStream_t stream) {
    const float* x = (const float*)d_in[0];
    const int* ei = (const int*)d_in[1];
    const int* src = ei;
    const int* dst = ei + NE;
    const int* batch = (const int*)d_in[2];
    const float *W[3], *b[3], *g[3], *beta[3];
    for (int l = 0; l < 3; ++l) {
        W[l]    = (const float*)d_in[3 + 4 * l];
        b[l]    = (const float*)d_in[4 + 4 * l];
        g[l]    = (const float*)d_in[5 + 4 * l];
        beta[l] = (const float*)d_in[6 + 4 * l];
    }
    float* out = (float*)d_out;
    float* gout = out + (size_t)NN * 384;

    char* ws = (char*)d_ws;
    size_t off = 0;
    auto alloc = [&](size_t bytes) -> char* {
        off = (off + 255) & ~(size_t)255;
        char* p = ws + off;
        off += bytes;
        return p;
    };
    uint4* hm        = (uint4*)alloc((size_t)NN * 256);       // bf16 rows, 256 B each
    float* act       = (float*)alloc((size_t)NN * 128 * 4);
    int2*  epair     = (int2*)alloc((size_t)NE * 8);
    int*   deg       = (int*)alloc((size_t)NN * 4);
    int*   cursor    = (int*)alloc((size_t)NN * 4);
    int*   row_start = (int*)alloc((size_t)(NN + 1) * 4);
    float* dinv      = (float*)alloc((size_t)NN * 4);
    int*   bsum      = (int*)alloc(512 * 4);
    float* bnst      = (float*)alloc(6 * 128 * 4);
    (void)ws_size;

    hipMemsetAsync(deg, 0, (size_t)NN * 4, stream);
    hipMemsetAsync(cursor, 0, (size_t)NN * 4, stream);
    hipMemsetAsync(bnst, 0, 6 * 128 * 4, stream);
    hipMemsetAsync(gout, 0, (size_t)NG * 384 * 4, stream);

    int nbN = (NN + 255) / 256;     // 391
    int nbE = (NE + 255) / 256;     // 6250

    k_hist<<<nbE, 256, 0, stream>>>(dst, deg);
    k_dinv<<<nbN, 256, 0, stream>>>(deg, dinv);
    k_blockscan<<<nbN, 256, 0, stream>>>(deg, row_start, bsum);
    k_scanb<<<1, 512, 0, stream>>>(bsum, nbN, row_start);
    k_scanadd<<<nbN, 256, 0, stream>>>(row_start, bsum);
    k_fill<<<nbE, 256, 0, stream>>>(src, dst, dinv, row_start, cursor, epair);

    for (int l = 0; l < 3; ++l) {
        const float* X = (l == 0) ? x : (out + (size_t)(l - 1) * 128);
        int ldx = (l == 0) ? 128 : 384;
        k_gemm<<<(NN + 63) / 64, 256, 0, stream>>>(X, ldx, W[l], hm);
        k_agg<<<2048, 256, 0, stream>>>(hm, epair, row_start, dinv, b[l], act,
                                        bnst + l * 256, bnst + l * 256 + 128);
        k_norm<<<(NN + 63) / 64, 128, 0, stream>>>(act, bnst + l * 256, bnst + l * 256 + 128,
                                                   g[l], beta[l], batch, out, gout, l * 128);
    }
}

// Round 3
// 769.223 us; speedup vs baseline: 1.2916x; 1.0395x over previous
//
#include <hip/hip_runtime.h>

#define NN 100000
#define NE 1600000
#define NG 128
#define BN_EPS 1e-5f

typedef short s16x8 __attribute__((ext_vector_type(8)));
typedef float f32x4 __attribute__((ext_vector_type(4)));

static __device__ __forceinline__ unsigned short f2bf(float f) {
    unsigned u = __float_as_uint(f);
    u += 0x7fffu + ((u >> 16) & 1u);   // RNE
    return (unsigned short)(u >> 16);
}
static __device__ __forceinline__ unsigned packbf(float a, float b) {
    return (unsigned)f2bf(a) | ((unsigned)f2bf(b) << 16);
}
static __device__ __forceinline__ float bf_lo(unsigned u) { return __uint_as_float(u << 16); }
static __device__ __forceinline__ float bf_hi(unsigned u) { return __uint_as_float(u & 0xffff0000u); }

// ---------------- degree histogram ----------------
__global__ __launch_bounds__(256) void k_hist(const int* __restrict__ dst, int* __restrict__ deg) {
    int e = blockIdx.x * 256 + threadIdx.x;
    if (e < NE) atomicAdd(&deg[dst[e]], 1);
}

__global__ __launch_bounds__(256) void k_dinv(const int* __restrict__ deg, float* __restrict__ dinv) {
    int n = blockIdx.x * 256 + threadIdx.x;
    if (n < NN) dinv[n] = rsqrtf((float)deg[n] + 1.0f);
}

// ---------------- prefix scan over deg -> row_start ----------------
__global__ __launch_bounds__(256) void k_blockscan(const int* __restrict__ deg, int* __restrict__ excl,
                                                   int* __restrict__ bsum) {
    __shared__ int s[256];
    int t = threadIdx.x;
    int i = blockIdx.x * 256 + t;
    int v = (i < NN) ? deg[i] : 0;
    s[t] = v;
    __syncthreads();
    for (int o = 1; o < 256; o <<= 1) {
        int add = (t >= o) ? s[t - o] : 0;
        __syncthreads();
        s[t] += add;
        __syncthreads();
    }
    if (i < NN) excl[i] = s[t] - v;
    if (t == 255) bsum[blockIdx.x] = s[255];
}

__global__ __launch_bounds__(512) void k_scanb(int* __restrict__ bsum, int nb, int* __restrict__ row_start) {
    __shared__ int s[512];
    int t = threadIdx.x;
    int v = (t < nb) ? bsum[t] : 0;
    s[t] = v;
    __syncthreads();
    for (int o = 1; o < 512; o <<= 1) {
        int add = (t >= o) ? s[t - o] : 0;
        __syncthreads();
        s[t] += add;
        __syncthreads();
    }
    if (t < nb) bsum[t] = s[t] - v;
    if (t == nb - 1) row_start[NN] = s[t];
}

__global__ __launch_bounds__(256) void k_scanadd(int* __restrict__ row_start, const int* __restrict__ bsum) {
    int i = blockIdx.x * 256 + threadIdx.x;
    if (i < NN) row_start[i] += bsum[blockIdx.x];
}

// ---------------- CSR fill ----------------
__global__ __launch_bounds__(256) void k_fill(const int* __restrict__ src, const int* __restrict__ dst,
                                              const float* __restrict__ dinv, const int* __restrict__ row_start,
                                              int* __restrict__ cursor, int2* __restrict__ epair) {
    int e = blockIdx.x * 256 + threadIdx.x;
    if (e >= NE) return;
    int s = src[e], d = dst[e];
    float cf = dinv[s] * dinv[d];
    int pos = row_start[d] + atomicAdd(&cursor[d], 1);
    epair[pos] = make_int2(s, __float_as_int(cf));
}

// ---------------- degree bucket sort: hist (LDS pre-reduce) ----------------
__global__ __launch_bounds__(256) void k_dhist(const int* __restrict__ deg, int* __restrict__ dcount) {
    __shared__ int lc[64];
    int t = threadIdx.x;
    if (t < 64) lc[t] = 0;
    __syncthreads();
    int n = blockIdx.x * 256 + t;
    if (n < NN) {
        int b = min(deg[n], 63);
        atomicAdd(&lc[b], 1);
    }
    __syncthreads();
    if (t < 64 && lc[t]) atomicAdd(&dcount[t], lc[t]);
}

// 64-entry exclusive scan -> cursor
__global__ __launch_bounds__(64) void k_dscan(const int* __restrict__ dcount, int* __restrict__ dcur) {
    __shared__ int s[64];
    int t = threadIdx.x;
    int v = dcount[t];
    s[t] = v;
    __syncthreads();
    for (int o = 1; o < 64; o <<= 1) {
        int add = (t >= o) ? s[t - o] : 0;
        __syncthreads();
        s[t] += add;
        __syncthreads();
    }
    dcur[t] = s[t] - v;
}

__global__ __launch_bounds__(256) void k_dscatter(const int* __restrict__ deg, int* __restrict__ dcur,
                                                  int* __restrict__ perm) {
    __shared__ int lc[64], lbase[64];
    int t = threadIdx.x;
    if (t < 64) lc[t] = 0;
    __syncthreads();
    int n = blockIdx.x * 256 + t;
    int b = 0, myoff = 0;
    if (n < NN) {
        b = min(deg[n], 63);
        myoff = atomicAdd(&lc[b], 1);
    }
    __syncthreads();
    if (t < 64 && lc[t]) lbase[t] = atomicAdd(&dcur[t], lc[t]);
    __syncthreads();
    if (n < NN) perm[lbase[b] + myoff] = n;
}

// ---------------- x -> bf16 cast ----------------
__global__ __launch_bounds__(256) void k_cast(const float* __restrict__ x, uint4* __restrict__ xb) {
    int i = blockIdx.x * 256 + threadIdx.x;   // 1.6M groups of 8 floats
    if (i >= NN * 16) return;
    float4 a = *(const float4*)(x + (size_t)i * 8);
    float4 b = *(const float4*)(x + (size_t)i * 8 + 4);
    uint4 o;
    o.x = packbf(a.x, a.y);
    o.y = packbf(a.z, a.w);
    o.z = packbf(b.x, b.y);
    o.w = packbf(b.z, b.w);
    xb[i] = o;
}

// ---------------- W -> MFMA fragment order (bf16) ----------------
// Wf[((ks*8+nb)*64 + lane)*8 + j] = bf16(W[ks*32 + (lane>>4)*8 + j][nb*16 + (lane&15)])
__global__ __launch_bounds__(64) void k_wfrag(const float* __restrict__ W, ushort* __restrict__ Wf) {
    int unit = blockIdx.x;          // 0..31: ks = unit>>3, nb = unit&7
    int lane = threadIdx.x;
    int ks = unit >> 3, nb = unit & 7;
    int n = nb * 16 + (lane & 15);
    int k0 = ks * 32 + (lane >> 4) * 8;
    ushort o[8];
#pragma unroll
    for (int j = 0; j < 8; ++j) o[j] = f2bf(W[(size_t)(k0 + j) * 128 + n]);
    ushort* p = Wf + ((size_t)unit * 64 + lane) * 8;
#pragma unroll
    for (int j = 0; j < 8; ++j) p[j] = o[j];
}

// ---------------- MFMA GEMM: hm_bf16[N][128] = Xb_bf16[N][128] @ W ----------------
__global__ __launch_bounds__(256) void k_gemm(const ushort* __restrict__ Xb, const ushort* __restrict__ Wf,
                                              ushort* __restrict__ hm) {
    int tid = threadIdx.x;
    int wid = tid >> 6, lane = tid & 63;
    int r0 = blockIdx.x * 64 + wid * 16;
    int m = lane & 15, g = lane >> 4;
    int xrow = r0 + m;
    int xr = (xrow < NN) ? xrow : (NN - 1);
    const ushort* Xrow = Xb + (size_t)xr * 128 + g * 8;
    f32x4 acc[8];
#pragma unroll
    for (int nb = 0; nb < 8; ++nb) acc[nb] = (f32x4){0.f, 0.f, 0.f, 0.f};
#pragma unroll
    for (int ks = 0; ks < 4; ++ks) {
        s16x8 af = *(const s16x8*)(Xrow + ks * 32);
#pragma unroll
        for (int nb = 0; nb < 8; ++nb) {
            s16x8 wf = *(const s16x8*)(Wf + ((size_t)(ks * 8 + nb) * 64 + lane) * 8);
            acc[nb] = __builtin_amdgcn_mfma_f32_16x16x32_bf16(wf, af, acc[nb], 0, 0, 0);
        }
    }
    if (xrow < NN) {
        ushort* orow = hm + (size_t)xrow * 128 + g * 4;
#pragma unroll
        for (int nb = 0; nb < 8; ++nb) {
            ushort4 o;
            o.x = f2bf(acc[nb][0]);
            o.y = f2bf(acc[nb][1]);
            o.z = f2bf(acc[nb][2]);
            o.w = f2bf(acc[nb][3]);
            *(ushort4*)(orow + nb * 16) = o;
        }
    }
}

// ---------------- aggregate + bias + relu + fused BN stats ----------------
// wave-autonomous: each wave claims 4-node units from its shard counter
__global__ __launch_bounds__(256) void k_agg(const uint4* __restrict__ hm, const int2* __restrict__ epair,
                                             const int* __restrict__ rs, const float* __restrict__ dinv,
                                             const int* __restrict__ perm, int* __restrict__ ctr,
                                             const float* __restrict__ bias, float* __restrict__ act,
                                             float* __restrict__ bnsum, float* __restrict__ bnsq) {
    __shared__ float ssum[128], ssq[128];
    int tid = threadIdx.x;
    if (tid < 128) { ssum[tid] = 0.f; ssq[tid] = 0.f; }
    __syncthreads();
    int lane = tid & 63;
    int wid = tid >> 6;
    int tx = tid & 15, ny = (tid >> 4) & 3;
    int shard = (blockIdx.x * 4 + wid) & 7;
    float b4[8];
    {
        float4 b0 = *(const float4*)(bias + tx * 8);
        float4 b1 = *(const float4*)(bias + tx * 8 + 4);
        b4[0] = b0.x; b4[1] = b0.y; b4[2] = b0.z; b4[3] = b0.w;
        b4[4] = b1.x; b4[5] = b1.y; b4[6] = b1.z; b4[7] = b1.w;
    }
    float st_s[8], st_q[8];
#pragma unroll
    for (int k = 0; k < 8; ++k) { st_s[k] = 0.f; st_q[k] = 0.f; }

    while (true) {
        int t;
        if (lane == 0) t = atomicAdd(&ctr[shard * 32], 1);
        t = __shfl(t, 0);
        if (t >= 3125) break;
        int unit = shard + t * 8;           // strided shards sample the degree-sort uniformly
        int n = perm[unit * 4 + ny];
        float di = dinv[n];
        float sc = di * di;
        float a[8];
        uint4 h = hm[(size_t)n * 16 + tx];
        a[0] = sc * bf_lo(h.x); a[1] = sc * bf_hi(h.x);
        a[2] = sc * bf_lo(h.y); a[3] = sc * bf_hi(h.y);
        a[4] = sc * bf_lo(h.z); a[5] = sc * bf_hi(h.z);
        a[6] = sc * bf_lo(h.w); a[7] = sc * bf_hi(h.w);
        int i = rs[n], e1 = rs[n + 1];
        for (; i + 8 <= e1; i += 8) {
            int2 ep[8];
#pragma unroll
            for (int u = 0; u < 8; ++u) ep[u] = epair[i + u];
            uint4 v[8];
#pragma unroll
            for (int u = 0; u < 8; ++u) v[u] = hm[(size_t)ep[u].x * 16 + tx];
#pragma unroll
            for (int u = 0; u < 8; ++u) {
                float c = __int_as_float(ep[u].y);
                a[0] += c * bf_lo(v[u].x); a[1] += c * bf_hi(v[u].x);
                a[2] += c * bf_lo(v[u].y); a[3] += c * bf_hi(v[u].y);
                a[4] += c * bf_lo(v[u].z); a[5] += c * bf_hi(v[u].z);
                a[6] += c * bf_lo(v[u].w); a[7] += c * bf_hi(v[u].w);
            }
        }
        if (i + 4 <= e1) {
            int2 ep[4];
#pragma unroll
            for (int u = 0; u < 4; ++u) ep[u] = epair[i + u];
            uint4 v[4];
#pragma unroll
            for (int u = 0; u < 4; ++u) v[u] = hm[(size_t)ep[u].x * 16 + tx];
#pragma unroll
            for (int u = 0; u < 4; ++u) {
                float c = __int_as_float(ep[u].y);
                a[0] += c * bf_lo(v[u].x); a[1] += c * bf_hi(v[u].x);
                a[2] += c * bf_lo(v[u].y); a[3] += c * bf_hi(v[u].y);
                a[4] += c * bf_lo(v[u].z); a[5] += c * bf_hi(v[u].z);
                a[6] += c * bf_lo(v[u].w); a[7] += c * bf_hi(v[u].w);
            }
            i += 4;
        }
        for (; i < e1; ++i) {
            int2 e0 = epair[i];
            uint4 v0 = hm[(size_t)e0.x * 16 + tx];
            float c0 = __int_as_float(e0.y);
            a[0] += c0 * bf_lo(v0.x); a[1] += c0 * bf_hi(v0.x);
            a[2] += c0 * bf_lo(v0.y); a[3] += c0 * bf_hi(v0.y);
            a[4] += c0 * bf_lo(v0.z); a[5] += c0 * bf_hi(v0.z);
            a[6] += c0 * bf_lo(v0.w); a[7] += c0 * bf_hi(v0.w);
        }
#pragma unroll
        for (int k = 0; k < 8; ++k) {
            float v = fmaxf(a[k] + b4[k], 0.f);
            a[k] = v;
            st_s[k] += v;
            st_q[k] += v * v;
        }
        float* ap = act + (size_t)n * 128 + tx * 8;
        *(float4*)ap       = make_float4(a[0], a[1], a[2], a[3]);
        *(float4*)(ap + 4) = make_float4(a[4], a[5], a[6], a[7]);
    }
#pragma unroll
    for (int k = 0; k < 8; ++k) {
        atomicAdd(&ssum[tx * 8 + k], st_s[k]);
        atomicAdd(&ssq[tx * 8 + k], st_q[k]);
    }
    __syncthreads();
    if (tid < 128) {
        atomicAdd(&bnsum[tid], ssum[tid]);
        atomicAdd(&bnsq[tid], ssq[tid]);
    }
}

// ---------------- normalize + write h_cat + pool + bf16 X for next layer ----------------
__global__ __launch_bounds__(128) void k_norm(const float* __restrict__ act, const float* __restrict__ bnsum,
                                              const float* __restrict__ bnsq, const float* __restrict__ gam,
                                              const float* __restrict__ bet, const int* __restrict__ batch,
                                              float* __restrict__ out, float* __restrict__ gout, int lofs,
                                              ushort* __restrict__ xb) {
    int c = threadIdx.x;
    int n0 = blockIdx.x * 64;
    if (n0 >= NN) return;
    int n1 = n0 + 64; if (n1 > NN) n1 = NN;
    float mean = bnsum[c] / (float)NN;
    float var = bnsq[c] / (float)NN - mean * mean;
    float rstd = rsqrtf(fmaxf(var, 0.f) + BN_EPS);
    float scale = gam[c] * rstd;
    float shift = bet[c] - mean * scale;
    int cur = batch[n0];
    float acc = 0.f;
    for (int n = n0; n < n1; ++n) {
        float z = act[(size_t)n * 128 + c] * scale + shift;
        out[(size_t)n * 384 + lofs + c] = z;
        if (xb) xb[(size_t)n * 128 + c] = f2bf(z);
        int bn = batch[n];
        if (bn != cur) {
            atomicAdd(&gout[(size_t)cur * 384 + lofs + c], acc);
            acc = 0.f;
            cur = bn;
        }
        acc += z;
    }
    atomicAdd(&gout[(size_t)cur * 384 + lofs + c], acc);
}

extern "C" void kernel_launch(void* const* d_in, const int* in_sizes, int n_in,
                              void* d_out, int out_size, void* d_ws, size_t ws_size,
                              hipStream_t stream) {
    const float* x = (const float*)d_in[0];
    const int* ei = (const int*)d_in[1];
    const int* src = ei;
    const int* dst = ei + NE;
    const int* batch = (const int*)d_in[2];
    const float *W[3], *b[3], *g[3], *beta[3];
    for (int l = 0; l < 3; ++l) {
        W[l]    = (const float*)d_in[3 + 4 * l];
        b[l]    = (const float*)d_in[4 + 4 * l];
        g[l]    = (const float*)d_in[5 + 4 * l];
        beta[l] = (const float*)d_in[6 + 4 * l];
    }
    float* out = (float*)d_out;
    float* gout = out + (size_t)NN * 384;

    char* ws = (char*)d_ws;
    size_t off = 0;
    auto alloc = [&](size_t bytes) -> char* {
        off = (off + 255) & ~(size_t)255;
        char* p = ws + off;
        off += bytes;
        return p;
    };
    ushort* hx       = (ushort*)alloc((size_t)NN * 256);      // bf16 rows: X input AND gemm output (aliased)
    float*  act      = (float*)alloc((size_t)NN * 128 * 4);
    int2*   epair    = (int2*)alloc((size_t)NE * 8);
    int*    deg      = (int*)alloc((size_t)NN * 4);
    int*    cursor   = (int*)alloc((size_t)NN * 4);
    int*    row_start= (int*)alloc((size_t)(NN + 1) * 4);
    float*  dinv     = (float*)alloc((size_t)NN * 4);
    int*    perm     = (int*)alloc((size_t)NN * 4);
    int*    bsum     = (int*)alloc(512 * 4);
    float*  bnst     = (float*)alloc(6 * 128 * 4);
    ushort* Wf       = (ushort*)alloc(3 * 16384 * 2);
    int*    misc     = (int*)alloc(1024 * 4);   // dcount[64], dcur[64], ctr[3][8*32]
    int* dcount = misc;
    int* dcur   = misc + 64;
    int* ctrs   = misc + 128;
    (void)ws_size;

    hipMemsetAsync(deg, 0, (size_t)NN * 4, stream);
    hipMemsetAsync(cursor, 0, (size_t)NN * 4, stream);
    hipMemsetAsync(misc, 0, 1024 * 4, stream);
    hipMemsetAsync(bnst, 0, 6 * 128 * 4, stream);
    hipMemsetAsync(gout, 0, (size_t)NG * 384 * 4, stream);

    int nbN = (NN + 255) / 256;     // 391
    int nbE = (NE + 255) / 256;     // 6250

    k_hist<<<nbE, 256, 0, stream>>>(dst, deg);
    k_dinv<<<nbN, 256, 0, stream>>>(deg, dinv);
    k_blockscan<<<nbN, 256, 0, stream>>>(deg, row_start, bsum);
    k_scanb<<<1, 512, 0, stream>>>(bsum, nbN, row_start);
    k_scanadd<<<nbN, 256, 0, stream>>>(row_start, bsum);
    k_fill<<<nbE, 256, 0, stream>>>(src, dst, dinv, row_start, cursor, epair);
    k_dhist<<<nbN, 256, 0, stream>>>(deg, dcount);
    k_dscan<<<1, 64, 0, stream>>>(dcount, dcur);
    k_dscatter<<<nbN, 256, 0, stream>>>(deg, dcur, perm);
    k_cast<<<(NN * 16 + 255) / 256, 256, 0, stream>>>(x, (uint4*)hx);
    for (int l = 0; l < 3; ++l) k_wfrag<<<32, 64, 0, stream>>>(W[l], Wf + l * 16384);

    for (int l = 0; l < 3; ++l) {
        k_gemm<<<(NN + 63) / 64, 256, 0, stream>>>(hx, Wf + l * 16384, hx);
        k_agg<<<2048, 256, 0, stream>>>((const uint4*)hx, epair, row_start, dinv, perm,
                                        ctrs + l * 256, b[l], act,
                                        bnst + l * 256, bnst + l * 256 + 128);
        k_norm<<<(NN + 63) / 64, 128, 0, stream>>>(act, bnst + l * 256, bnst + l * 256 + 128,
                                                   g[l], beta[l], batch, out, gout, l * 128,
                                                   (l < 2) ? hx : (ushort*)nullptr);
    }
}